// Round 4
// baseline (465.991 us; speedup 1.0000x reference)
//
#include <hip/hip_runtime.h>
#include <hip/hip_fp16.h>
#include <math.h>

#define N_CELLS 16384
#define HID 512
#define IND 512
#define NB 512              // blocks (exactly 2 per CU x 256 CUs -> all resident)
#define NT 512              // threads (8 waves)

// ---- workspace layout (bytes) ----
#define CNT_OFF   0                                   // int[4]: bar0, bar1, gate (memset to 0 by host)
#define EMIS_OFF  128                                 // float2[512]: per-channel emission sums
#define LAS_OFF   16384                               // int[N_CELLS]: lasing flags
#define VPART_OFF (LAS_OFF + N_CELLS*4)               // float2[NB]
#define ROT_OFF   (1<<20)                             // u32 Y^T[512][16384]: packed half2(re,im)
#define NST_OFF   (ROT_OFF + (size_t)N_CELLS*HID*4)   // u32 NST^T[512][16384]

typedef unsigned int u32;

__device__ inline __half2 u2h(u32 u) { union { u32 u; __half2 h; } x; x.u = u; return x.h; }
__device__ inline u32 h2u(__half2 h) { union { u32 u; __half2 h; } x; x.h = h; return x.u; }
__device__ inline u32 packh2(float re, float im) { return h2u(__floats2half2_rn(re, im)); }
__device__ inline float2 unph2(u32 u) { __half2 h = u2h(u); return make_float2(__low2float(h), __high2float(h)); }

#if __has_builtin(__builtin_amdgcn_fdot2)
typedef _Float16 hv2 __attribute__((ext_vector_type(2)));
__device__ inline float dot2u(u32 a, u32 b) {
    union { u32 u; hv2 h; } x, y; x.u = a; y.u = b;
    return __builtin_amdgcn_fdot2(x.h, y.h, 0.f, false);
}
#else
__device__ inline float dot2u(u32 a, u32 b) {
    float2 af = unph2(a), bf = unph2(b);
    return fmaf(af.x, bf.x, af.y * bf.y);
}
#endif

__device__ inline void accnb(__half2& acc, u32 y, u32 q) {
    float d = dot2u(y, q);
    acc = __hfma2(__float2half2_rn(d), u2h(q), acc);
}

__device__ inline u32 fincell(u32 y, __half2 acc, int las, float& emR, float& emI) {
    float2 yf = unph2(y);
    float a  = fmaf(yf.x, yf.x, yf.y * yf.y);   // |y|^2 = |s|
    float rs = rsqrtf(a);
    float sq = a * rs;
    float2 af = make_float2(__low2float(acc), __high2float(acc));
    float nr = 0.7f * sq * yf.x + 0.002f * rs * af.x;
    float ni = 0.7f * sq * yf.y + 0.002f * rs * af.y;
    if (las) { emR += nr; emI += ni; }
    return packh2(nr, ni);
}

__device__ inline u32 rot1(float re, float im, float w) {
    float sc = rsqrtf(sqrtf(fmaf(re, re, im * im)));
    float s, c;
    __sincosf(0.1f * w, &s, &c);
    return packh2((re * c - im * s) * sc, (re * s + im * c) * sc);
}

__device__ inline float dot4(float4 a, float4 b) {
    return a.x * b.x + a.y * b.y + a.z * b.z + a.w * b.w;
}

// All NB blocks are resident by construction (2/CU). Bounded spin: fail-fast
// (wrong result, no hang) if residency assumption ever breaks.
__device__ inline void gridbar(int* bar) {
    __syncthreads();
    if (threadIdx.x == 0) {
        __threadfence();
        atomicAdd(bar, 1);
        for (int it = 0; it < (1 << 22); ++it) {
            if (__hip_atomic_load(bar, __ATOMIC_ACQUIRE, __HIP_MEMORY_SCOPE_AGENT) >= NB) break;
            __builtin_amdgcn_s_sleep(2);
        }
    }
    __syncthreads();
    __threadfence();
}

// ---------------------------------------------------------------------------
__global__ __launch_bounds__(NT, 4) void k_mega(
        const float* __restrict__ cr, const float* __restrict__ ci,
        const float* __restrict__ pv, const float* __restrict__ x,
        const float* __restrict__ pW, const float* __restrict__ pb,
        const float* __restrict__ excited,
        const float* __restrict__ cavr, const float* __restrict__ cavi,
        const float* __restrict__ dW, const float* __restrict__ db,
        u32* __restrict__ yt, u32* __restrict__ nstT,
        int* __restrict__ lasv, float2* __restrict__ emisT,
        float2* __restrict__ vpart,
        int* __restrict__ bars, float* __restrict__ out) {
    __shared__ __align__(16) u32 col[N_CELLS];          // 64 KiB, re-partitioned per phase
    int b = blockIdx.x, t = threadIdx.x;
    int w = t >> 6, lane = t & 63;

    // ================= Phase A: rot-transpose (4 tiles of 64c x 64ch) ======
    {
        const float4* cr4 = (const float4*)cr;
        const float4* ci4 = (const float4*)ci;
        const float4* pv4 = (const float4*)pv;
#pragma unroll 1
        for (int tt = 0; tt < 4; ++tt) {
            int tile_id = b * 4 + tt, cb = tile_id >> 3, hb = tile_id & 7;
            float4 A[2], Bv[2], Wv[2];
            int row[2], c4[2];
#pragma unroll
            for (int jj = 0; jj < 2; ++jj) {            // 6 loads in flight
                int idx = t + NT * jj;
                row[jj] = idx >> 4; c4[jj] = idx & 15;
                size_t g = (size_t)(cb * 64 + row[jj]) * 128 + hb * 16 + c4[jj];
                A[jj] = cr4[g]; Bv[jj] = ci4[g]; Wv[jj] = pv4[g];
            }
#pragma unroll
            for (int jj = 0; jj < 2; ++jj) {
                u32* dst = &col[row[jj] * 65 + (c4[jj] << 2)];
                dst[0] = rot1(A[jj].x, Bv[jj].x, Wv[jj].x);
                dst[1] = rot1(A[jj].y, Bv[jj].y, Wv[jj].y);
                dst[2] = rot1(A[jj].z, Bv[jj].z, Wv[jj].z);
                dst[3] = rot1(A[jj].w, Bv[jj].w, Wv[jj].w);
            }
            __syncthreads();
#pragma unroll
            for (int jj = 0; jj < 2; ++jj) {
                int idx = t + NT * jj;
                int chr = idx >> 4, q = idx & 15;
                uint4 v;
                v.x = col[(q * 4 + 0) * 65 + chr];
                v.y = col[(q * 4 + 1) * 65 + chr];
                v.z = col[(q * 4 + 2) * 65 + chr];
                v.w = col[(q * 4 + 3) * 65 + chr];
                ((uint4*)(yt + (size_t)(hb * 64 + chr) * N_CELLS + cb * 64))[q] = v;
            }
            __syncthreads();
        }
    }
    // ================= Phase A: pump (wave per cell, 4 cells/wave) =========
    {
        const float4* x4 = (const float4*)x;
        float4 xa0 = x4[lane], xa1 = x4[lane + 64];
        int cbase = b * 32 + w * 4;
        float4 wv[4][2];
#pragma unroll
        for (int k = 0; k < 4; ++k) {                   // 8 loads in flight
            const float4* w4 = (const float4*)(pW + (size_t)(cbase + k) * IND);
            wv[k][0] = w4[lane]; wv[k][1] = w4[lane + 64];
        }
#pragma unroll
        for (int k = 0; k < 4; ++k) {
            float acc = dot4(wv[k][0], xa0) + dot4(wv[k][1], xa1);
#pragma unroll
            for (int o = 32; o; o >>= 1) acc += __shfl_xor(acc, o, 64);
            if (lane == 0) {
                int cell = cbase + k;
                float p = 1.f / (1.f + expf(-(acc + pb[cell])));
                float e = excited[cell] * 0.95f + p * 0.05f;
                e = fminf(fmaxf(e, 0.f), 1.f);
                lasv[cell] = (e > 0.5f) ? 1 : 0;
            }
        }
    }
    gridbar(&bars[0]);

    // ================= Phase B: coupling (block = channel b) ===============
    {
        const uint4* src = (const uint4*)(yt + (size_t)b * N_CELLS);
        uint4 st[8];
#pragma unroll
        for (int k = 0; k < 8; ++k) st[k] = src[t + NT * k];   // 8 in flight
        uint4* cd = (uint4*)col;
#pragma unroll
        for (int k = 0; k < 8; ++k) cd[t + NT * k] = st[k];
        __syncthreads();

        float emR = 0.f, emI = 0.f;
        int nlo = 0;
        uint4* outp = (uint4*)(nstT + (size_t)b * N_CELLS);
        const int4* l4 = (const int4*)lasv;
#pragma unroll 2
        for (int j = 0; j < 8; ++j) {
            int s = t + NT * j;
            int c = s << 2;
            uint4 sq = *(const uint4*)&col[c];
            __half2 z = __floats2half2_rn(0.f, 0.f);
            __half2 a0 = z, a1 = z, a2 = z, a3 = z;
#pragma unroll
            for (int bb = 2; bb < 14; ++bb) {           // 12 external flips
                uint4 q = *(const uint4*)&col[c ^ (1 << bb)];
                accnb(a0, sq.x, q.x);
                accnb(a1, sq.y, q.y);
                accnb(a2, sq.z, q.z);
                accnb(a3, sq.w, q.w);
            }
            u32 qm = col[(c - 1) & (N_CELLS - 1)];
            u32 qp = col[(c + 4) & (N_CELLS - 1)];
            accnb(a0, sq.x, sq.y); accnb(a0, sq.x, sq.z); accnb(a0, sq.x, qm);
            accnb(a1, sq.y, sq.x); accnb(a1, sq.y, sq.w); accnb(a1, sq.y, sq.z);
            accnb(a2, sq.z, sq.w); accnb(a2, sq.z, sq.x); accnb(a2, sq.z, sq.y);
            accnb(a3, sq.w, sq.z); accnb(a3, sq.w, sq.y); accnb(a3, sq.w, qp);
            int4 lv = l4[s];
            nlo += lv.x + lv.y + lv.z + lv.w;
            uint4 ov;
            ov.x = fincell(sq.x, a0, lv.x, emR, emI);
            ov.y = fincell(sq.y, a1, lv.y, emR, emI);
            ov.z = fincell(sq.z, a2, lv.z, emR, emI);
            ov.w = fincell(sq.w, a3, lv.w, emR, emI);
            outp[s] = ov;
        }
        __syncthreads();                                // col reads done
#pragma unroll
        for (int o = 32; o; o >>= 1) {
            emR += __shfl_xor(emR, o, 64);
            emI += __shfl_xor(emI, o, 64);
            nlo += __shfl_xor(nlo, o, 64);
        }
        float* scr = (float*)col;
        int* iscr = (int*)col;
        if (lane == 0) { scr[w] = emR; scr[8 + w] = emI; iscr[16 + w] = nlo; }
        __syncthreads();
        if (t == 0) {
            float sr = 0.f, si = 0.f; int sn = 0;
#pragma unroll
            for (int k = 0; k < 8; ++k) { sr += scr[k]; si += scr[8 + k]; sn += iscr[16 + k]; }
            emisT[b] = make_float2(sr, si);
            // sn is the FULL lasing count (this block scanned every cell).
            // Stash it in shared for Phase C1 (col[24] untouched until then).
            iscr[24] = sn;
        }
    }
    gridbar(&bars[1]);

    // ================= Phase C1: cavity (redundant per block) ==============
    float* scav = (float*)&col[8192];                   // re[512]|im[512]|phase[512]
    {
        int nl = ((int*)col)[24];                       // block-local total == global nl
        float inv = (nl > 0) ? 0.2f / (float)nl : 0.f;
        float crv = cavr[t], civ = cavi[t];
        float2 e = emisT[t];
        scav[t]        = (nl > 0) ? 0.8f * crv + e.x * inv : crv;
        scav[512 + t]  = (nl > 0) ? 0.8f * civ + e.y * inv : civ;
        scav[1024 + t] = atan2f(civ, crv);
        __syncthreads();
    }
    // ================= pred row b (wave 0 only) ============================
    if (t < 64) {
        const float4* w4 = (const float4*)(dW + (size_t)b * (2 * HID));
        const float4* o4 = (const float4*)scav;
        float a2 = 0.f;
#pragma unroll
        for (int q = 0; q < 4; ++q) {
            float4 a = w4[t + 64 * q];
            float4 bx = o4[t + 64 * q];
            a2 += dot4(a, bx);
        }
#pragma unroll
        for (int o = 32; o; o >>= 1) a2 += __shfl_xor(a2, o, 64);
        if (t == 0) out[b] = a2 + db[b];
    }
    // ================= Phase C2: finalize 32 cells (2 x 16-cell tiles) =====
    float ts1 = 0.f, ts2 = 0.f;
#pragma unroll 1
    for (int tt = 0; tt < 2; ++tt) {
        int c0 = b * 32 + tt * 16;
        uint4 ld[4]; int chv[4], qv[4];
#pragma unroll
        for (int jj = 0; jj < 4; ++jj) {                // 4 loads in flight
            int idx = t + NT * jj;                      // 0..2047
            chv[jj] = idx >> 2; qv[jj] = idx & 3;
            ld[jj] = ((const uint4*)(nstT + (size_t)chv[jj] * N_CELLS + c0))[qv[jj]];
        }
        __syncthreads();                                // prior col readers done
#pragma unroll
        for (int jj = 0; jj < 4; ++jj) {
#pragma unroll
            for (int e = 0; e < 4; ++e) {
                int cell = qv[jj] * 4 + e;
                int sw = chv[jj] ^ (((e ^ qv[jj]) & 1) << 4);
                col[cell * HID + sw] = ((const u32*)&ld[jj])[e];
            }
        }
        __syncthreads();
        int cell = t >> 5, kk = t & 31;                 // 32 threads per cell
        int lasc = lasv[c0 + cell];
        int sb = ((cell ^ (cell >> 2)) & 1) << 4;
        const u32* trow = &col[cell * HID];
        float sa = 0.f, sa2 = 0.f, mx = 0.f;
#pragma unroll 4
        for (int i = 0; i < 16; ++i) {
            int ch = kk + 32 * i;
            float2 vf = unph2(trow[ch ^ sb]);
            float vx = vf.x, vy = vf.y;
            if (lasc) {
                float r = sqrtf(fmaf(vx, vx, vy * vy));
                float lk = 0.3f * scav[1024 + ch] + 0.7f * atan2f(vy, vx);
                float sn, cs;
                __sincosf(lk, &sn, &cs);
                vx = r * cs; vy = r * sn;
            }
            vx += 0.05f * scav[ch];
            vy += 0.05f * scav[512 + ch];
            float a2v = fmaf(vx, vx, vy * vy);
            float a = sqrtf(a2v);
            sa += a; sa2 += a2v; mx = fmaxf(mx, a);
        }
#pragma unroll
        for (int o = 1; o <= 16; o <<= 1) {
            sa += __shfl_xor(sa, o, 64);
            sa2 += __shfl_xor(sa2, o, 64);
            mx = fmaxf(mx, __shfl_xor(mx, o, 64));
        }
        float invm = 1.f / (mx + 1e-8f);
        float s1 = sa * invm, s2 = sa2 * invm * invm;
        s1 += __shfl_xor(s1, 32, 64);
        s2 += __shfl_xor(s2, 32, 64);
        ts1 += s1; ts2 += s2;
    }
    __syncthreads();
    {
        float* scr = (float*)col;
        if (lane == 0) { scr[w] = ts1; scr[8 + w] = ts2; }
        __syncthreads();
        if (t == 0) {
            float s1 = 0.f, s2 = 0.f;
#pragma unroll
            for (int k = 0; k < 8; ++k) { s1 += scr[k]; s2 += scr[8 + k]; }
            vpart[b] = make_float2(s1, s2);
        }
    }
    // ================= var: counter-gated last block =======================
    {
        int* iflag = (int*)&col[64];
        if (t == 0) {
            __threadfence();
            int old = atomicAdd(&bars[2], 1);
            *iflag = (old == NB - 1) ? 1 : 0;
        }
        __syncthreads();
        if (*iflag) {
            __threadfence();
            double d1 = (double)vpart[t].x;
            double d2 = (double)vpart[t].y;
#pragma unroll
            for (int o = 32; o; o >>= 1) { d1 += __shfl_xor(d1, o, 64); d2 += __shfl_xor(d2, o, 64); }
            double* dscr = (double*)col;
            if (lane == 0) { dscr[w] = d1; dscr[8 + w] = d2; }
            __syncthreads();
            if (t == 0) {
                double t1 = 0.0, t2 = 0.0;
#pragma unroll
                for (int k = 0; k < 8; ++k) { t1 += dscr[k]; t2 += dscr[8 + k]; }
                double nn = (double)N_CELLS * (double)HID;
                double mean = t1 / nn;
                out[IND] = (float)(t2 / nn - mean * mean);
            }
        }
    }
}

// ---------------------------------------------------------------------------
extern "C" void kernel_launch(void* const* d_in, const int* in_sizes, int n_in,
                              void* d_out, int out_size, void* d_ws, size_t ws_size,
                              hipStream_t stream) {
    const float* x       = (const float*)d_in[0];
    const float* pump_W  = (const float*)d_in[1];
    const float* pump_b  = (const float*)d_in[2];
    const float* dec_W   = (const float*)d_in[3];
    const float* dec_b   = (const float*)d_in[4];
    const float* cs_re   = (const float*)d_in[5];
    const float* cs_im   = (const float*)d_in[6];
    const float* excited = (const float*)d_in[7];
    const float* pvel    = (const float*)d_in[8];
    const float* cav_re  = (const float*)d_in[9];
    const float* cav_im  = (const float*)d_in[10];
    // d_in[11] (neighbors) not needed: hypercube+ring recomputed on-chip

    float* out = (float*)d_out;
    char* ws = (char*)d_ws;
    int*    bars  = (int*)(ws + CNT_OFF);
    float2* emisT = (float2*)(ws + EMIS_OFF);
    int*    lasv  = (int*)(ws + LAS_OFF);
    float2* vpart = (float2*)(ws + VPART_OFF);
    u32*    yt    = (u32*)(ws + ROT_OFF);
    u32*    nstT  = (u32*)(ws + NST_OFF);

    hipMemsetAsync(ws + CNT_OFF, 0, 16, stream);
    k_mega<<<NB, NT, 0, stream>>>(
        cs_re, cs_im, pvel, x, pump_W, pump_b, excited, cav_re, cav_im,
        dec_W, dec_b, yt, nstT, lasv, emisT, vpart, bars, out);
}

// Round 5
// 261.934 us; speedup vs baseline: 1.7790x; 1.7790x over previous
//
#include <hip/hip_runtime.h>
#include <hip/hip_fp16.h>
#include <math.h>

#define N_CELLS 16384
#define HID 512
#define IND 512

// ---- k_front roles ----
#define ROT_BLOCKS  2048    // 256 cell-tiles x 8 ch-tiles, each 64 cells x 64 ch
#define PUMP_BLOCKS 4096    // 4 cells per block (wave per cell)

// ---- k_finall ----
#define CPB 16                          // cells per cell-block (LDS tile 16x512 u32 = 32 KB)
#define CELL_BLOCKS (N_CELLS / CPB)     // 1024
#define PRED_BLOCKS 128                 // 4 pred rows per block

// ---- workspace layout (bytes) ----
#define CNT_OFF   0                                   // int[2]: cnt[0]=k_coup tail, cnt[1]=k_finall tail
#define EMIS_OFF  128                                 // float2[512]: per-channel emission sums
#define CAV_OFF   4352                                // float[1536]: cav_new re[512] | im[512] | old phase[512]
#define LAS_OFF   16384                               // int[N_CELLS]: lasing flags
#define VPART_OFF (LAS_OFF + N_CELLS*4)               // float2[CELL_BLOCKS]
#define ROT_OFF   (1<<20)                             // u32 Y^T[512][16384]: packed half2(re,im), y=s/sqrt(|s|)
#define NST_OFF   (ROT_OFF + (size_t)N_CELLS*HID*4)   // u32 NST^T[512][16384]: packed half2(re,im)

typedef unsigned int u32;

__device__ inline __half2 u2h(u32 u) { union { u32 u; __half2 h; } x; x.u = u; return x.h; }
__device__ inline u32 h2u(__half2 h) { union { u32 u; __half2 h; } x; x.h = h; return x.u; }
__device__ inline u32 packh2(float re, float im) { return h2u(__floats2half2_rn(re, im)); }
__device__ inline float2 unph2(u32 u) { __half2 h = u2h(u); return make_float2(__low2float(h), __high2float(h)); }

#if __has_builtin(__builtin_amdgcn_fdot2)
typedef _Float16 hv2 __attribute__((ext_vector_type(2)));
__device__ inline float dot2u(u32 a, u32 b) {
    union { u32 u; hv2 h; } x, y; x.u = a; y.u = b;
    return __builtin_amdgcn_fdot2(x.h, y.h, 0.f, false);   // re*re' + im*im' in f32
}
#else
__device__ inline float dot2u(u32 a, u32 b) {
    float2 af = unph2(a), bf = unph2(b);
    return fmaf(af.x, bf.x, af.y * bf.y);
}
#endif

// acc += d * q  where d = y.q  (cos-coupling identity on y = s/sqrt(|s|))
__device__ inline void accnb(__half2& acc, u32 y, u32 q) {
    float d = dot2u(y, q);
    acc = __hfma2(__float2half2_rn(d), u2h(q), acc);
}

// new = 0.7*s + 0.002*|s|^{-1/2}*acc ; s = |s|^{1/2} * y ; emission sum if lasing
__device__ inline u32 fincell(u32 y, __half2 acc, int las, float& emR, float& emI) {
    float2 yf = unph2(y);
    float a  = fmaf(yf.x, yf.x, yf.y * yf.y);   // |y|^2 = |s|
    float rs = rsqrtf(a);
    float sq = a * rs;
    float2 af = make_float2(__low2float(acc), __high2float(acc));
    float nr = 0.7f * sq * yf.x + 0.002f * rs * af.x;
    float ni = 0.7f * sq * yf.y + 0.002f * rs * af.y;
    if (las) { emR += nr; emI += ni; }
    return packh2(nr, ni);
}

// rotate by exp(i*0.1*w), scale by |s|^{-1/2}, pack half2(re,im)
__device__ inline u32 rot1(float re, float im, float w) {
    float sc = rsqrtf(sqrtf(fmaf(re, re, im * im)));
    float s, c;
    __sincosf(0.1f * w, &s, &c);
    return packh2((re * c - im * s) * sc, (re * s + im * c) * sc);
}

__device__ inline float dot4(float4 a, float4 b) {
    return a.x * b.x + a.y * b.y + a.z * b.z + a.w * b.w;
}

// ---------------------------------------------------------------------------
// Kernel 1: rotation + |s|^{-1/2} scaling, written TRANSPOSED (Y^T[ch][cell])
// via a 64x64 LDS transpose tile (pitch 65). ALL 12 input float4 loads are
// hoisted into registers before any compute (round-4 lesson: VGPR=24 meant
// ~2 loads in flight -> latency-bound at 1.9 TB/s). launch_bounds(256,2)
// frees the register allocator.
__global__ __launch_bounds__(256, 2) void k_front(const float* __restrict__ cr,
        const float* __restrict__ ci, const float* __restrict__ pv,
        u32* __restrict__ yt,
        const float* __restrict__ x, const float* __restrict__ pW,
        const float* __restrict__ pb, const float* __restrict__ excited,
        int* __restrict__ lasing, int* __restrict__ cnt) {
    int b = blockIdx.x, tid = threadIdx.x;
    if (b < ROT_BLOCKS) {
        __shared__ u32 tile[64 * 65];
        int cb = b >> 3, hb = b & 7;
        const float4* cr4 = (const float4*)cr;
        const float4* ci4 = (const float4*)ci;
        const float4* pv4 = (const float4*)pv;
        float4 A[4], Bv[4], Wv[4];
        int row[4], c4[4];
#pragma unroll
        for (int j = 0; j < 4; ++j) {                   // 12 loads in flight
            int idx = tid + 256 * j;
            row[j] = idx >> 4; c4[j] = idx & 15;
            size_t g = (size_t)(cb * 64 + row[j]) * 128 + hb * 16 + c4[j];
            A[j] = cr4[g]; Bv[j] = ci4[g]; Wv[j] = pv4[g];
        }
#pragma unroll
        for (int j = 0; j < 4; ++j) {
            u32* dst = &tile[row[j] * 65 + (c4[j] << 2)];
            dst[0] = rot1(A[j].x, Bv[j].x, Wv[j].x);
            dst[1] = rot1(A[j].y, Bv[j].y, Wv[j].y);
            dst[2] = rot1(A[j].z, Bv[j].z, Wv[j].z);
            dst[3] = rot1(A[j].w, Bv[j].w, Wv[j].w);
        }
        if (b == 0 && tid == 0) { cnt[0] = 0; cnt[1] = 0; }
        __syncthreads();
        uint4 v[4];
#pragma unroll
        for (int j = 0; j < 4; ++j) {                   // gather all, then store all
            int idx = tid + 256 * j;
            int chr = idx >> 4, q = idx & 15;
            v[j].x = tile[(q * 4 + 0) * 65 + chr];
            v[j].y = tile[(q * 4 + 1) * 65 + chr];
            v[j].z = tile[(q * 4 + 2) * 65 + chr];
            v[j].w = tile[(q * 4 + 3) * 65 + chr];
        }
#pragma unroll
        for (int j = 0; j < 4; ++j) {
            int idx = tid + 256 * j;
            int chr = idx >> 4, q = idx & 15;
            ((uint4*)(yt + (size_t)(hb * 64 + chr) * N_CELLS + cb * 64))[q] = v[j];
        }
    } else {
        // pump = sigmoid(x . pump_W[cell] + pb); lasing flag. Wave per cell.
        int gtid = (b - ROT_BLOCKS) * 256 + tid;
        int cell = gtid >> 6, lane = gtid & 63;
        const float4* w4 = (const float4*)(pW + (size_t)cell * IND);
        const float4* x4 = (const float4*)x;
        float4 wa0 = w4[lane], wa1 = w4[lane + 64];     // both loads in flight
        float4 xb0 = x4[lane], xb1 = x4[lane + 64];
        float acc = dot4(wa0, xb0) + dot4(wa1, xb1);
#pragma unroll
        for (int o = 32; o; o >>= 1) acc += __shfl_xor(acc, o, 64);
        if (lane == 0) {
            float p = 1.f / (1.f + expf(-(acc + pb[cell])));
            float e = excited[cell] * 0.95f + p * 0.05f;
            e = fminf(fmaxf(e, 0.f), 1.f);
            lasing[cell] = (e > 0.5f) ? 1 : 0;
        }
    }
}

// ---------------------------------------------------------------------------
// Kernel 2: neighbor coupling, one block per CHANNEL (column staged in LDS,
// all 16 accesses/element from LDS; neighbors recomputed; emission via block
// reduction; counter-gated tail computes cavity_new + old phase once).
// Round-4 changes: column staging register-staged 8-deep (x2 rounds), lasv
// int4 load software-pipelined one j ahead, launch_bounds(256,2).
__global__ __launch_bounds__(256, 2) void k_coup(const u32* __restrict__ yt,
                                                 const int* __restrict__ lasv,
                                                 u32* __restrict__ nstT,
                                                 float2* __restrict__ emisT,
                                                 const float* __restrict__ cavr,
                                                 const float* __restrict__ cavi,
                                                 float* __restrict__ cavws,
                                                 int* __restrict__ cnt) {
    __shared__ __align__(16) u32 col[N_CELLS];          // exactly 64 KiB
    int ch = blockIdx.x, tid = threadIdx.x;
    const uint4* src = (const uint4*)(yt + (size_t)ch * N_CELLS);
    uint4* cdst = (uint4*)col;
    {
        uint4 st[8];
#pragma unroll
        for (int k = 0; k < 8; ++k) st[k] = src[tid + 256 * k];      // 8 in flight
#pragma unroll
        for (int k = 0; k < 8; ++k) cdst[tid + 256 * k] = st[k];
#pragma unroll
        for (int k = 0; k < 8; ++k) st[k] = src[tid + 256 * (k + 8)];
#pragma unroll
        for (int k = 0; k < 8; ++k) cdst[tid + 256 * (k + 8)] = st[k];
    }
    __syncthreads();

    float emR = 0.f, emI = 0.f;
    int nlo = 0;
    uint4* outp = (uint4*)(nstT + (size_t)ch * N_CELLS);
    const int4* l4 = (const int4*)lasv;
    int4 lv_next = l4[tid];                             // pipeline lasv by 1 iter
#pragma unroll 2
    for (int j = 0; j < 16; ++j) {
        int s = tid + 256 * j;
        int4 lv = lv_next;
        if (j < 15) lv_next = l4[s + 256];
        int c = s << 2;                                 // quad base cell
        uint4 sq = *(const uint4*)&col[c];
        __half2 z = __floats2half2_rn(0.f, 0.f);
        __half2 a0 = z, a1 = z, a2 = z, a3 = z;
#pragma unroll
        for (int bb = 2; bb < 14; ++bb) {               // 12 external flips
            uint4 q = *(const uint4*)&col[c ^ (1 << bb)];
            accnb(a0, sq.x, q.x);
            accnb(a1, sq.y, q.y);
            accnb(a2, sq.z, q.z);
            accnb(a3, sq.w, q.w);
        }
        u32 qm = col[(c - 1) & (N_CELLS - 1)];          // ring extra of cell c   (even -> c-1)
        u32 qp = col[(c + 4) & (N_CELLS - 1)];          // ring extra of cell c+3 (odd  -> c+4)
        accnb(a0, sq.x, sq.y); accnb(a0, sq.x, sq.z); accnb(a0, sq.x, qm);
        accnb(a1, sq.y, sq.x); accnb(a1, sq.y, sq.w); accnb(a1, sq.y, sq.z);
        accnb(a2, sq.z, sq.w); accnb(a2, sq.z, sq.x); accnb(a2, sq.z, sq.y);
        accnb(a3, sq.w, sq.z); accnb(a3, sq.w, sq.y); accnb(a3, sq.w, qp);
        nlo += lv.x + lv.y + lv.z + lv.w;
        uint4 ov;
        ov.x = fincell(sq.x, a0, lv.x, emR, emI);
        ov.y = fincell(sq.y, a1, lv.y, emR, emI);
        ov.z = fincell(sq.z, a2, lv.z, emR, emI);
        ov.w = fincell(sq.w, a3, lv.w, emR, emI);
        outp[s] = ov;
    }
    __syncthreads();                                    // col reads done -> reuse as scratch
#pragma unroll
    for (int o = 32; o; o >>= 1) {
        emR += __shfl_xor(emR, o, 64);
        emI += __shfl_xor(emI, o, 64);
        nlo += __shfl_xor(nlo, o, 64);
    }
    float* scr = (float*)col;
    int* iscr = (int*)col;
    int wid = tid >> 6, lane = tid & 63;
    if (lane == 0) { scr[wid] = emR; scr[4 + wid] = emI; iscr[8 + wid] = nlo; }
    __syncthreads();
    if (tid == 0) {
        emisT[ch] = make_float2(scr[0] + scr[1] + scr[2] + scr[3],
                                scr[4] + scr[5] + scr[6] + scr[7]);
        __threadfence();
        int old = atomicAdd(cnt, 1);
        iscr[12] = (old == HID - 1) ? 1 : 0;
    }
    __syncthreads();
    if (iscr[12]) {
        // ---- TAIL: compute cavity_new + old phase once ----
        __threadfence();
        int nl = iscr[8] + iscr[9] + iscr[10] + iscr[11];
        float inv = (nl > 0) ? 0.2f / (float)nl : 0.f;
#pragma unroll
        for (int k2 = 0; k2 < 2; ++k2) {
            int i = tid + 256 * k2;
            float crv = cavr[i], civ = cavi[i];
            float2 e = emisT[i];
            cavws[i]        = (nl > 0) ? 0.8f * crv + e.x * inv : crv;
            cavws[512 + i]  = (nl > 0) ? 0.8f * civ + e.y * inv : civ;
            cavws[1024 + i] = atan2f(civ, crv);
        }
    }
}

// ---------------------------------------------------------------------------
// Kernel 3: finalize + var + pred. Cell role: block = 16 cells; the
// [512ch x 16cell] slab is loaded with coalesced 64B row segments into a
// 32KB XOR-swizzled LDS tile, then 16 threads/cell stream 32 ch each.
// Round-4 change: ALL 8 slab uint4 loads hoisted before the scatter.
__global__ __launch_bounds__(256, 2) void k_finall(const u32* __restrict__ nstT,
        const int* __restrict__ lasv, const float* __restrict__ cavws,
        const float* __restrict__ dW, const float* __restrict__ db,
        float2* __restrict__ vpart, int* __restrict__ cnt2,
        float* __restrict__ out) {
    int b = blockIdx.x, t = threadIdx.x;
    int wid = t >> 6, lane = t & 63;
    if (b < CELL_BLOCKS) {
        __shared__ __align__(16) u32 tile[CPB * HID];   // 32 KB
        __shared__ __align__(16) float scav[1536];      // cav re|im|phase
        __shared__ float w1[4], w2[4];
        __shared__ int slast;
        __shared__ double l1s[4], l2s[4];

        int c0 = b * CPB;
        uint4 ld[8]; int chv[8], qv[8];
#pragma unroll
        for (int j = 0; j < 8; ++j) {                   // 8 loads in flight
            int idx = t + 256 * j;                      // 0..2047
            chv[j] = idx >> 2; qv[j] = idx & 3;
            ld[j] = ((const uint4*)(nstT + (size_t)chv[j] * N_CELLS + c0))[qv[j]];
        }
        const float4* c4p = (const float4*)cavws;
#pragma unroll
        for (int k2 = 0; k2 < 2; ++k2) {
            int i = t + 256 * k2;
            if (i < 384) ((float4*)scav)[i] = c4p[i];
        }
#pragma unroll
        for (int j = 0; j < 8; ++j) {
#pragma unroll
            for (int e = 0; e < 4; ++e) {
                int cell = qv[j] * 4 + e;
                int sw = chv[j] ^ (((e ^ qv[j]) & 1) << 4);
                tile[cell * HID + sw] = ((const u32*)&ld[j])[e];
            }
        }
        __syncthreads();

        int cell = t >> 4, kk = t & 15;
        int lasc = lasv[c0 + cell];
        int swb = ((cell ^ (cell >> 2)) & 1) << 4;
        const u32* trow = &tile[cell * HID];
        float sa = 0.f, sa2 = 0.f, mx = 0.f;
#pragma unroll 8
        for (int i = 0; i < 32; ++i) {
            int ch = kk + 16 * i;
            float2 vf = unph2(trow[ch ^ swb]);
            float vx = vf.x, vy = vf.y;
            if (lasc) {
                float r = sqrtf(fmaf(vx, vx, vy * vy));
                float lk = 0.3f * scav[1024 + ch] + 0.7f * atan2f(vy, vx);
                float sn, cs;
                __sincosf(lk, &sn, &cs);
                vx = r * cs; vy = r * sn;
            }
            vx += 0.05f * scav[ch];
            vy += 0.05f * scav[512 + ch];
            float a2v = fmaf(vx, vx, vy * vy);
            float a = sqrtf(a2v);
            sa += a; sa2 += a2v; mx = fmaxf(mx, a);
        }
        // per-cell reduce over the 16 lanes of the cell group
#pragma unroll
        for (int o = 1; o < 16; o <<= 1) {
            sa += __shfl_xor(sa, o, 64);
            sa2 += __shfl_xor(sa2, o, 64);
            mx = fmaxf(mx, __shfl_xor(mx, o, 64));
        }
        float invm = 1.f / (mx + 1e-8f);
        float s1 = sa * invm, s2 = sa2 * invm * invm;
        // sum the 4 cell groups of the wave
        s1 += __shfl_xor(s1, 16, 64); s2 += __shfl_xor(s2, 16, 64);
        s1 += __shfl_xor(s1, 32, 64); s2 += __shfl_xor(s2, 32, 64);
        if (lane == 0) { w1[wid] = s1; w2[wid] = s2; }
        __syncthreads();
        if (t == 0) {
            vpart[b] = make_float2(w1[0] + w1[1] + w1[2] + w1[3],
                                   w2[0] + w2[1] + w2[2] + w2[3]);
            __threadfence();
            int old = atomicAdd(cnt2, 1);
            slast = (old == CELL_BLOCKS - 1) ? 1 : 0;
        }
        __syncthreads();
        if (slast) {
            __threadfence();
            double d1 = (double)vpart[t].x + (double)vpart[t + 256].x
                      + (double)vpart[t + 512].x + (double)vpart[t + 768].x;
            double d2 = (double)vpart[t].y + (double)vpart[t + 256].y
                      + (double)vpart[t + 512].y + (double)vpart[t + 768].y;
#pragma unroll
            for (int o = 32; o; o >>= 1) { d1 += __shfl_xor(d1, o, 64); d2 += __shfl_xor(d2, o, 64); }
            if (lane == 0) { l1s[wid] = d1; l2s[wid] = d2; }
            __syncthreads();
            if (t == 0) {
                double t1 = l1s[0] + l1s[1] + l1s[2] + l1s[3];
                double t2 = l2s[0] + l2s[1] + l2s[2] + l2s[3];
                double nn = (double)N_CELLS * (double)HID;
                double mean = t1 / nn;
                out[IND] = (float)(t2 / nn - mean * mean);
            }
        }
    } else {
        // ---- pred role: wave wid computes row j; cavity read direct (L2-hot) ----
        int j = (b - CELL_BLOCKS) * 4 + wid;
        const float4* w4 = (const float4*)(dW + (size_t)j * (2 * HID));
        const float4* o4 = (const float4*)cavws;
        float a2 = 0.f;
#pragma unroll
        for (int tt = 0; tt < 4; ++tt) {
            float4 a = w4[lane + 64 * tt];
            float4 bx = o4[lane + 64 * tt];
            a2 += a.x * bx.x + a.y * bx.y + a.z * bx.z + a.w * bx.w;
        }
#pragma unroll
        for (int o = 32; o; o >>= 1) a2 += __shfl_xor(a2, o, 64);
        if (lane == 0) out[j] = a2 + db[j];
    }
}

// ---------------------------------------------------------------------------
extern "C" void kernel_launch(void* const* d_in, const int* in_sizes, int n_in,
                              void* d_out, int out_size, void* d_ws, size_t ws_size,
                              hipStream_t stream) {
    const float* x       = (const float*)d_in[0];
    const float* pump_W  = (const float*)d_in[1];
    const float* pump_b  = (const float*)d_in[2];
    const float* dec_W   = (const float*)d_in[3];
    const float* dec_b   = (const float*)d_in[4];
    const float* cs_re   = (const float*)d_in[5];
    const float* cs_im   = (const float*)d_in[6];
    const float* excited = (const float*)d_in[7];
    const float* pvel    = (const float*)d_in[8];
    const float* cav_re  = (const float*)d_in[9];
    const float* cav_im  = (const float*)d_in[10];
    // d_in[11] (neighbors) not needed: hypercube+ring recomputed on-chip

    float* out = (float*)d_out;
    char* ws = (char*)d_ws;
    int*    cnt   = (int*)(ws + CNT_OFF);
    float2* emisT = (float2*)(ws + EMIS_OFF);
    float*  cavws = (float*)(ws + CAV_OFF);
    int*    lasv  = (int*)(ws + LAS_OFF);
    float2* vpart = (float2*)(ws + VPART_OFF);
    u32*    yt    = (u32*)(ws + ROT_OFF);
    u32*    nstT  = (u32*)(ws + NST_OFF);

    k_front<<<ROT_BLOCKS + PUMP_BLOCKS, 256, 0, stream>>>(
        cs_re, cs_im, pvel, yt, x, pump_W, pump_b, excited, lasv, cnt);
    k_coup<<<HID, 256, 0, stream>>>(yt, lasv, nstT, emisT, cav_re, cav_im, cavws, cnt);
    k_finall<<<CELL_BLOCKS + PRED_BLOCKS, 256, 0, stream>>>(
        nstT, lasv, cavws, dec_W, dec_b, vpart, cnt + 1, out);
}